// Round 4
// baseline (44.114 us; speedup 1.0000x reference)
//
#include <hip/hip_runtime.h>
#include <math.h>

#define DD 256
#define DEPTH 4
#define XD 48
#define NBLK 16
#define NTHR 256

// cls-position-only network (round-1 derivation, absmax 0.0).
// Round 4: ONE persistent kernel. Hand-rolled grid barrier:
//  - cross-block activations (xc/zv/hv, ~2KB) via agent-scope relaxed atomics
//    (sc1 -> LLC; no L1/L2 caching of shared data, and NO acquire/release
//    fences, so weights stay L2-resident -- round 2's failure mode avoided)
//  - barrier = monotonic LLC counter: fetch_add on arrive, spin on
//    cnt >= phase*NBLK. __syncthreads() before arrival drains all sc1 stores
//    (compiler emits s_waitcnt vmcnt(0) before s_barrier).
// ws: [0,256) xc | [256,512) zv | [512,768) hv | float[1024] -> counter.

__device__ __forceinline__ float llc_loadf(const float* p) {
    return __hip_atomic_load(p, __ATOMIC_RELAXED, __HIP_MEMORY_SCOPE_AGENT);
}
__device__ __forceinline__ void llc_storef(float* p, float v) {
    __hip_atomic_store(p, v, __ATOMIC_RELAXED, __HIP_MEMORY_SCOPE_AGENT);
}

__device__ __forceinline__ void grid_bar(unsigned int* cnt, unsigned int target) {
    __syncthreads();                       // drains vmcnt(0): sc1 stores at LLC
    if (threadIdx.x == 0) {
        __hip_atomic_fetch_add(cnt, 1u, __ATOMIC_RELAXED, __HIP_MEMORY_SCOPE_AGENT);
        while (__hip_atomic_load(cnt, __ATOMIC_RELAXED, __HIP_MEMORY_SCOPE_AGENT) < target)
            __builtin_amdgcn_s_sleep(1);
    }
    __syncthreads();
}

__global__ void netmamba_init(unsigned int* cnt) { *cnt = 0u; }

__global__ __launch_bounds__(NTHR, 1)
void netmamba_persist(const float* __restrict__ cls_token,
                      const float* __restrict__ pos_embed,
                      const float* __restrict__ norm_w,
                      const float* __restrict__ in_proj_w,
                      const float* __restrict__ conv_w,
                      const float* __restrict__ conv_b,
                      const float* __restrict__ x_proj_w,
                      const float* __restrict__ dt_proj_w,
                      const float* __restrict__ dt_proj_b,
                      const float* __restrict__ D_skip,
                      const float* __restrict__ out_proj_w,
                      const float* __restrict__ norm_f_w,
                      float* __restrict__ out,
                      float* __restrict__ ws)
{
    const int tid = threadIdx.x, bid = blockIdx.x;
    float* xc_g = ws;
    float* zv_g = ws + DD;
    float* hv_g = ws + 2 * DD;
    unsigned int* cnt = (unsigned int*)(ws + 1024);

    __shared__ float hn[DD], xcl[DD], yv[DD], xdbl[XD];
    __shared__ float4 partA[32][8];   // in_proj partials (4 KB)
    __shared__ float4 partB[64][4];   // out_proj partials (4 KB)
    __shared__ float xp[XD][4];
    __shared__ float red[4];
    __shared__ float rstd_s;

    float res_reg = 0.f;              // residual element tid, redundant per block
    unsigned int phase = 0;

    for (int L = 0; L < DEPTH; ++L) {
        // ===== phase A: residual + rmsnorm (redundant) + in_proj slice =====
        float rn;
        if (L == 0) rn = cls_token[tid] + pos_embed[50 * DD + tid];
        else        rn = res_reg + llc_loadf(&hv_g[tid]);
        res_reg = rn;

        float ss = rn * rn;
        #pragma unroll
        for (int o = 32; o > 0; o >>= 1) ss += __shfl_down(ss, o, 64);
        if ((tid & 63) == 0) red[tid >> 6] = ss;
        __syncthreads();
        if (tid == 0)
            rstd_s = rsqrtf((red[0] + red[1] + red[2] + red[3]) * (1.f / DD) + 1e-5f);
        __syncthreads();
        hn[tid] = rn * rstd_s * norm_w[L * DD + tid];
        __syncthreads();

        // in_proj slice: global cols [32*bid, 32*bid+32) of 512
        {
            const float4* W4 = (const float4*)in_proj_w + (size_t)L * DD * 128;
            const int cg = tid & 7, seg = tid >> 3;     // 32 segs x 8 col4-groups
            const int col4 = bid * 8 + cg;
            float4 acc = make_float4(0.f, 0.f, 0.f, 0.f);
            #pragma unroll
            for (int i = 0; i < 8; ++i) {
                const int d = seg * 8 + i;
                const float h = hn[d];
                const float4 w = W4[(size_t)d * 128 + col4];
                acc.x += h * w.x; acc.y += h * w.y;
                acc.z += h * w.z; acc.w += h * w.w;
            }
            partA[seg][cg] = acc;
        }
        __syncthreads();
        if (tid < 32) {
            const float* pf = (const float*)partA;      // [seg*32 + localcol]
            float s = 0.f;
            #pragma unroll
            for (int g = 0; g < 32; ++g) s += pf[g * 32 + tid];
            const int gc = bid * 32 + tid;
            if (gc < DD) {
                const float pre = conv_w[(L * DD + gc) * 4 + 3] * s + conv_b[L * DD + gc];
                llc_storef(&xc_g[gc], pre / (1.f + __expf(-pre)));   // silu
            } else {
                llc_storef(&zv_g[gc - DD], s);
            }
        }
        ++phase;
        grid_bar(cnt, phase * NBLK);

        // ===== phase B: narrow path (redundant) + out_proj slice =====
        xcl[tid] = llc_loadf(&xc_g[tid]);
        const float zval = llc_loadf(&zv_g[tid]);
        __syncthreads();

        if (tid < 192) {                   // x_proj: 48 cols x 4 d-segments of 64
            const int j = tid >> 2, q = tid & 3;
            const float* Wx = x_proj_w + (size_t)L * DD * XD;
            float acc = 0.f;
            #pragma unroll 8
            for (int i = 0; i < 64; ++i) {
                const int d = q * 64 + i;
                acc += xcl[d] * Wx[(size_t)d * XD + j];
            }
            xp[j][q] = acc;
        }
        __syncthreads();
        if (tid < XD) xdbl[tid] = xp[tid][0] + xp[tid][1] + xp[tid][2] + xp[tid][3];
        __syncthreads();

        {
            const float* Wdt = dt_proj_w + (size_t)L * 16 * DD;
            float acc = dt_proj_b[L * DD + tid];
            #pragma unroll
            for (int r = 0; r < 16; ++r) acc += xdbl[r] * Wdt[r * DD + tid];
            const float dtv = fmaxf(acc, 0.f) + log1pf(__expf(-fabsf(acc)));  // softplus
            float sbc = 0.f;
            #pragma unroll
            for (int n = 0; n < 16; ++n) sbc += xdbl[16 + n] * xdbl[32 + n];  // B.C
            const float y = (dtv * sbc + D_skip[L * DD + tid]) * xcl[tid];
            yv[tid] = y * (zval / (1.f + __expf(-zval)));                     // * silu(z)
        }
        __syncthreads();

        // out_proj slice: global cols [16*bid, 16*bid+16) of 256
        {
            const float4* Wo = (const float4*)out_proj_w + (size_t)L * DD * 64;
            const int c = tid & 3, seg = tid >> 2;      // 64 segs x 4 col4-groups
            const int col4 = bid * 4 + c;
            float4 acc = make_float4(0.f, 0.f, 0.f, 0.f);
            #pragma unroll
            for (int i = 0; i < 4; ++i) {
                const int d = seg * 4 + i;
                const float y = yv[d];
                const float4 w = Wo[(size_t)d * 64 + col4];
                acc.x += y * w.x; acc.y += y * w.y;
                acc.z += y * w.z; acc.w += y * w.w;
            }
            partB[seg][c] = acc;
        }
        __syncthreads();
        #pragma unroll
        for (int off = 32; off >= 8; off >>= 1) {
            const int s = tid >> 2, c = tid & 3;
            if (s < off) {
                float4 a = partB[s][c], b = partB[s + off][c];
                a.x += b.x; a.y += b.y; a.z += b.z; a.w += b.w;
                partB[s][c] = a;
            }
            __syncthreads();
        }
        if (tid < 16) {
            const float* pf = (const float*)partB;      // [seg*16 + localcol]
            float s = 0.f;
            #pragma unroll
            for (int g = 0; g < 8; ++g) s += pf[g * 16 + tid];
            llc_storef(&hv_g[bid * 16 + tid], s);
        }
        ++phase;
        grid_bar(cnt, phase * NBLK);
    }

    // ===== final rmsnorm (redundant) + broadcast 16 rows per block =====
    {
        const float x = llc_loadf(&hv_g[tid]);
        float ss = x * x;
        #pragma unroll
        for (int o = 32; o > 0; o >>= 1) ss += __shfl_down(ss, o, 64);
        if ((tid & 63) == 0) red[tid >> 6] = ss;
        __syncthreads();
        if (tid == 0)
            rstd_s = rsqrtf((red[0] + red[1] + red[2] + red[3]) * (1.f / DD) + 1e-5f);
        __syncthreads();
        hn[tid] = x * rstd_s * norm_f_w[tid];
    }
    __syncthreads();
    {
        const float4* o4 = (const float4*)hn;
        float4* out4 = (float4*)out;
        #pragma unroll
        for (int k = 0; k < 4; ++k) {
            const int idx = k * NTHR + tid;             // 0..1023
            const int row = bid * 16 + (idx >> 6);
            out4[(size_t)row * 64 + (idx & 63)] = o4[idx & 63];
        }
    }
}

extern "C" void kernel_launch(void* const* d_in, const int* in_sizes, int n_in,
                              void* d_out, int out_size, void* d_ws, size_t ws_size,
                              hipStream_t stream) {
    // 0 x, 1 proj_w, 2 proj_b, 3 cls_token, 4 pos_embed, 5 norm_w, 6 in_proj_w,
    // 7 conv_w, 8 conv_b, 9 x_proj_w, 10 dt_proj_w, 11 dt_proj_b, 12 A_log,
    // 13 D_skip, 14 out_proj_w, 15 norm_f_w
    float* ws = (float*)d_ws;
    unsigned int* cnt = (unsigned int*)(ws + 1024);

    netmamba_init<<<dim3(1), dim3(1), 0, stream>>>(cnt);
    netmamba_persist<<<dim3(NBLK), dim3(NTHR), 0, stream>>>(
        (const float*)d_in[3], (const float*)d_in[4], (const float*)d_in[5],
        (const float*)d_in[6], (const float*)d_in[7], (const float*)d_in[8],
        (const float*)d_in[9], (const float*)d_in[10], (const float*)d_in[11],
        (const float*)d_in[13], (const float*)d_in[14], (const float*)d_in[15],
        (float*)d_out, ws);
}

// Round 5
// 43.930 us; speedup vs baseline: 1.0042x; 1.0042x over previous
//
#include <hip/hip_runtime.h>
#include <math.h>

#define DD 256
#define DEPTH 4
#define WPG 16              // wide blocks per layer-group
#define BPG 17              // +1 narrow block
#define NBLK (DEPTH * BPG)  // 68
#define NTHR 256

// ws float offsets
#define WS_XC   0
#define WS_ZV   256
#define WS_YV   512
#define WS_HV   1024        // hv[4][256] -> [1024,2048)
#define WS_FLAG 2048        // uint flags: A[L]=w[L*16], B[L]=w[(4+L)*16], C[L]=w[(8+L)*16]

// narrow LDS layout (floats in dyn): Wx[256][52] pad  | Wdt[16][256] | Dskip | dt_b
#define NX_WX   0
#define NX_WDT  13312
#define NX_DS   17408
#define NX_DB   17664
#define DYN_FLOATS 17920    // 71680 bytes

__device__ __forceinline__ float llc_loadf(const float* p) {
    return __hip_atomic_load(p, __ATOMIC_RELAXED, __HIP_MEMORY_SCOPE_AGENT);
}
__device__ __forceinline__ void llc_storef(float* p, float v) {
    __hip_atomic_store(p, v, __ATOMIC_RELAXED, __HIP_MEMORY_SCOPE_AGENT);
}
__device__ __forceinline__ unsigned llc_loadu(const unsigned* p) {
    return __hip_atomic_load(p, __ATOMIC_RELAXED, __HIP_MEMORY_SCOPE_AGENT);
}
__device__ __forceinline__ void flag_add(unsigned* p) {
    __hip_atomic_fetch_add(p, 1u, __ATOMIC_RELAXED, __HIP_MEMORY_SCOPE_AGENT);
}

__global__ void netmamba_init(unsigned* flags) { flags[threadIdx.x] = 0u; }

__global__ __launch_bounds__(NTHR, 1)
void netmamba_df(const float* __restrict__ cls_token,
                 const float* __restrict__ pos_embed,
                 const float* __restrict__ norm_w,
                 const float* __restrict__ in_proj_w,
                 const float* __restrict__ conv_w,
                 const float* __restrict__ conv_b,
                 const float* __restrict__ x_proj_w,
                 const float* __restrict__ dt_proj_w,
                 const float* __restrict__ dt_proj_b,
                 const float* __restrict__ D_skip,
                 const float* __restrict__ out_proj_w,
                 const float* __restrict__ norm_f_w,
                 float* __restrict__ out,
                 float* __restrict__ ws)
{
    extern __shared__ float dyn[];
    const int tid = threadIdx.x;
    const int bid = blockIdx.x;
    const int g   = bid / BPG;          // layer this block serves
    const int r   = bid % BPG;          // rank; WPG == narrow
    const bool narrow = (r == WPG);

    float* xc_g = ws + WS_XC;
    float* zv_g = ws + WS_ZV;
    float* yv_g = ws + WS_YV;
    float* hv_g = ws + WS_HV;
    unsigned* flags = (unsigned*)(ws + WS_FLAG);

    __shared__ float sh_a[DD];          // hn / xcl / final-vec
    __shared__ float sh_b[DD];          // partials / zvl
    __shared__ float sh_c[DD];          // yv-local / xp partials
    __shared__ float sh_d[64];          // conv3+cb (wide) / xdbl48 (narrow)
    __shared__ float red[4];
    __shared__ float rstd_s;

    // ================= prefetch (no sync deps; overlaps everything) ==========
    if (!narrow) {
        const float4* Gi = (const float4*)in_proj_w + (size_t)(g * DD) * 128 + r * 8;
        float4* Li = (float4*)dyn;                       // [256][8] f4
        #pragma unroll
        for (int k = 0; k < 8; ++k) {
            const int m = tid + k * 256;                 // m = d*8 + c4
            Li[m] = Gi[(size_t)(m >> 3) * 128 + (m & 7)];
        }
        const float4* Go = (const float4*)out_proj_w + (size_t)(g * DD) * 64 + r * 4;
        float4* Lo = (float4*)(dyn + 8192);              // [256][4] f4
        #pragma unroll
        for (int k = 0; k < 4; ++k) {
            const int m = tid + k * 256;                 // m = d*4 + c4
            Lo[m] = Go[(size_t)(m >> 2) * 64 + (m & 3)];
        }
        if (r < 8 && tid < 32) {
            const int gc = r * 32 + tid;
            sh_d[tid]      = conv_w[((size_t)g * DD + gc) * 4 + 3];
            sh_d[32 + tid] = conv_b[g * DD + gc];
        }
    } else {
        const float4* Gx = (const float4*)x_proj_w + (size_t)(g * DD) * 12;
        #pragma unroll
        for (int k = 0; k < 12; ++k) {
            const int m = tid + k * 256;                 // 0..3071
            const int d = m / 12, c4 = m % 12;
            *(float4*)(dyn + NX_WX + d * 52 + c4 * 4) = Gx[(size_t)d * 12 + c4];
        }
        const float4* Gd = (const float4*)dt_proj_w + (size_t)g * 1024;
        float4* Ld = (float4*)(dyn + NX_WDT);
        #pragma unroll
        for (int k = 0; k < 4; ++k) { const int m = tid + k * 256; Ld[m] = Gd[m]; }
        dyn[NX_DS + tid] = D_skip[g * DD + tid];
        dyn[NX_DB + tid] = dt_proj_b[g * DD + tid];
    }
    const float nf_reg = norm_f_w[tid];
    float iv_reg = 0.f, nw_reg = 0.f;
    if (!narrow) {
        iv_reg = cls_token[tid] + pos_embed[50 * DD + tid];
        nw_reg = norm_w[g * DD + tid];
    }
    __syncthreads();

    if (!narrow) {
        // ======== phase A: wait prev layer, residual+rmsnorm, in_proj ========
        if (g > 0) {
            if (tid == 0)
                while (llc_loadu(&flags[(8 + g - 1) * 16]) < WPG)
                    __builtin_amdgcn_s_sleep(1);
            __syncthreads();
        }
        float rn = iv_reg;
        for (int l = 0; l < g; ++l) rn += llc_loadf(&hv_g[l * DD + tid]);

        float ss = rn * rn;
        #pragma unroll
        for (int o = 32; o > 0; o >>= 1) ss += __shfl_down(ss, o, 64);
        if ((tid & 63) == 0) red[tid >> 6] = ss;
        __syncthreads();
        if (tid == 0)
            rstd_s = rsqrtf((red[0] + red[1] + red[2] + red[3]) * (1.f / DD) + 1e-5f);
        __syncthreads();
        sh_a[tid] = rn * rstd_s * nw_reg;
        __syncthreads();

        {   // in_proj: 32 cols; thread (q=tid>>5, c=tid&31): 32 MACs; 2-way LDS ok
            const int c = tid & 31, q = tid >> 5;
            float acc = 0.f;
            #pragma unroll
            for (int i = 0; i < 32; ++i) {
                const int d = q * 32 + i;
                acc += sh_a[d] * dyn[d * 32 + c];
            }
            sh_b[q * 32 + c] = acc;
        }
        __syncthreads();
        if (tid < 32) {
            float s = 0.f;
            #pragma unroll
            for (int p = 0; p < 8; ++p) s += sh_b[p * 32 + tid];
            const int gc = r * 32 + tid;
            if (r < 8) {
                const float pre = sh_d[tid] * s + sh_d[32 + tid];
                llc_storef(&xc_g[gc], pre / (1.f + __expf(-pre)));   // silu
            } else {
                llc_storef(&zv_g[gc - DD], s);
            }
        }
        __syncthreads();                       // drains sc1 stores (vmcnt 0)
        if (tid == 0) flag_add(&flags[g * 16]);            // flagA

        // ======== phase B: wait narrow, out_proj ========
        if (tid == 0)
            while (llc_loadu(&flags[(4 + g) * 16]) < 1)
                __builtin_amdgcn_s_sleep(1);
        __syncthreads();
        sh_c[tid] = llc_loadf(&yv_g[tid]);
        __syncthreads();
        {   // out_proj: 16 cols; d = i*16+q interleave -> 2-way LDS
            const int c2 = tid & 15, q2 = tid >> 4;
            const float* Lo = dyn + 8192;
            float acc = 0.f;
            #pragma unroll
            for (int i = 0; i < 16; ++i) {
                const int d = i * 16 + q2;
                acc += sh_c[d] * Lo[d * 16 + c2];
            }
            sh_b[q2 * 16 + c2] = acc;
        }
        __syncthreads();
        if (tid < 16) {
            float s = 0.f;
            #pragma unroll
            for (int p = 0; p < 16; ++p) s += sh_b[p * 16 + tid];
            llc_storef(&hv_g[g * DD + r * 16 + tid], s);
        }
        __syncthreads();
        if (tid == 0) flag_add(&flags[(8 + g) * 16]);      // flagC
    } else {
        // ======== narrow: x_proj + dt + scan(t=0) + gate ========
        if (tid == 0)
            while (llc_loadu(&flags[g * 16]) < WPG)
                __builtin_amdgcn_s_sleep(1);
        __syncthreads();
        sh_a[tid] = llc_loadf(&xc_g[tid]);
        sh_b[tid] = llc_loadf(&zv_g[tid]);
        __syncthreads();
        if (tid < 192) {                       // x_proj: j=tid>>2, q=tid&3, d=i*4+q
            const int j = tid >> 2, q = tid & 3;
            float acc = 0.f;
            #pragma unroll 8
            for (int i = 0; i < 64; ++i) {
                const int d = i * 4 + q;
                acc += sh_a[d] * dyn[NX_WX + d * 52 + j];
            }
            sh_c[j * 4 + q] = acc;
        }
        __syncthreads();
        if (tid < 48)
            sh_d[tid] = sh_c[tid * 4] + sh_c[tid * 4 + 1] + sh_c[tid * 4 + 2] + sh_c[tid * 4 + 3];
        __syncthreads();
        {
            const float* Wdt = dyn + NX_WDT;
            float acc = dyn[NX_DB + tid];
            #pragma unroll
            for (int rr = 0; rr < 16; ++rr) acc += sh_d[rr] * Wdt[rr * 256 + tid];
            const float dtv = fmaxf(acc, 0.f) + log1pf(__expf(-fabsf(acc))); // softplus
            float sbc = 0.f;
            #pragma unroll
            for (int n = 0; n < 16; ++n) sbc += sh_d[16 + n] * sh_d[32 + n]; // B.C
            const float y = (dtv * sbc + dyn[NX_DS + tid]) * sh_a[tid];
            const float z = sh_b[tid];
            llc_storef(&yv_g[tid], y * (z / (1.f + __expf(-z))));            // * silu(z)
        }
        __syncthreads();
        if (tid == 0) flag_add(&flags[(4 + g) * 16]);      // flagB
    }

    // ======== final: wait layer-3 hv, rmsnorm (redundant), write 4 rows ========
    if (tid == 0)
        while (llc_loadu(&flags[(8 + 3) * 16]) < WPG)
            __builtin_amdgcn_s_sleep(1);
    __syncthreads();
    {
        const float x = llc_loadf(&hv_g[3 * DD + tid]);
        float ss = x * x;
        #pragma unroll
        for (int o = 32; o > 0; o >>= 1) ss += __shfl_down(ss, o, 64);
        if ((tid & 63) == 0) red[tid >> 6] = ss;
        __syncthreads();
        if (tid == 0)
            rstd_s = rsqrtf((red[0] + red[1] + red[2] + red[3]) * (1.f / DD) + 1e-5f);
        __syncthreads();
        sh_a[tid] = x * rstd_s * nf_reg;
    }
    __syncthreads();
    if (bid < 64) {
        const int row = bid * 4 + (tid >> 6);
        const int cc  = tid & 63;
        const float4 v = make_float4(sh_a[cc * 4], sh_a[cc * 4 + 1],
                                     sh_a[cc * 4 + 2], sh_a[cc * 4 + 3]);
        ((float4*)out)[(size_t)row * 64 + cc] = v;
    }
}

extern "C" void kernel_launch(void* const* d_in, const int* in_sizes, int n_in,
                              void* d_out, int out_size, void* d_ws, size_t ws_size,
                              hipStream_t stream) {
    // 0 x, 1 proj_w, 2 proj_b, 3 cls_token, 4 pos_embed, 5 norm_w, 6 in_proj_w,
    // 7 conv_w, 8 conv_b, 9 x_proj_w, 10 dt_proj_w, 11 dt_proj_b, 12 A_log,
    // 13 D_skip, 14 out_proj_w, 15 norm_f_w
    float* ws = (float*)d_ws;
    unsigned* flags = (unsigned*)(ws + WS_FLAG);

    netmamba_init<<<dim3(1), dim3(256), 0, stream>>>(flags);
    netmamba_df<<<dim3(NBLK), dim3(NTHR), DYN_FLOATS * sizeof(float), stream>>>(
        (const float*)d_in[3], (const float*)d_in[4], (const float*)d_in[5],
        (const float*)d_in[6], (const float*)d_in[7], (const float*)d_in[8],
        (const float*)d_in[9], (const float*)d_in[10], (const float*)d_in[11],
        (const float*)d_in[13], (const float*)d_in[14], (const float*)d_in[15],
        (float*)d_out, ws);
}

// Round 6
// 38.343 us; speedup vs baseline: 1.1505x; 1.1457x over previous
//
#include <hip/hip_runtime.h>
#include <math.h>

#define DD 256
#define NL 4
#define WPL 16               // wide blocks per layer
#define NBLK (NL * WPL)      // 64
#define NTHR 256

// ws float offsets
#define WS_XC   0            // [256]
#define WS_ZV   256          // [256]
#define WS_RES  512          // res[4][256]; res[0] unused (iv computed in-block)
#define WS_HV3  1536         // [256] layer-3 mixer output
#define WS_FLAG 2048         // unsigned[8*32]: A[g]=f[g*32], C[g]=f[(4+g)*32]

// dynamic LDS float offsets (per block: 118784 B)
#define L_IN  0              // in_proj slice  [256][32]
#define L_OUT 8192           // out_proj slice [256][16]
#define L_XP  12288          // x_proj full    [256][52] (48 used, pad 52)
#define L_DT  25600          // dt_proj full   [16][256]
#define DYN_FLOATS 29696

static __device__ __forceinline__ float llc_loadf(const float* p) {
    return __hip_atomic_load(p, __ATOMIC_RELAXED, __HIP_MEMORY_SCOPE_AGENT);
}
static __device__ __forceinline__ void llc_storef(float* p, float v) {
    __hip_atomic_store(p, v, __ATOMIC_RELAXED, __HIP_MEMORY_SCOPE_AGENT);
}
static __device__ __forceinline__ unsigned llc_loadu(const unsigned* p) {
    return __hip_atomic_load(p, __ATOMIC_RELAXED, __HIP_MEMORY_SCOPE_AGENT);
}
static __device__ __forceinline__ void flag_add(unsigned* p) {
    __hip_atomic_fetch_add(p, 1u, __ATOMIC_RELAXED, __HIP_MEMORY_SCOPE_AGENT);
}

__global__ void netmamba_init(unsigned* flags) { flags[threadIdx.x] = 0u; }

__global__ __launch_bounds__(NTHR, 1)
void netmamba_df2(const float* __restrict__ cls_token,
                  const float* __restrict__ pos_embed,
                  const float* __restrict__ norm_w,
                  const float* __restrict__ in_proj_w,
                  const float* __restrict__ conv_w,
                  const float* __restrict__ conv_b,
                  const float* __restrict__ x_proj_w,
                  const float* __restrict__ dt_proj_w,
                  const float* __restrict__ dt_proj_b,
                  const float* __restrict__ D_skip,
                  const float* __restrict__ out_proj_w,
                  const float* __restrict__ norm_f_w,
                  float* __restrict__ out,
                  float* __restrict__ ws)
{
    extern __shared__ float dyn[];
    const int tid = threadIdx.x;
    const int bid = blockIdx.x;
    const int g = bid >> 4;          // layer
    const int r = bid & 15;          // rank within layer

    float* xc_g  = ws + WS_XC;
    float* zv_g  = ws + WS_ZV;
    float* res_g = ws + WS_RES;      // res_g + g*256
    float* hv3_g = ws + WS_HV3;
    unsigned* flags = (unsigned*)(ws + WS_FLAG);

    __shared__ float sh_res[DD];     // res[g] stash (phase A -> phase B)
    __shared__ float sh_vec[DD];     // hn (A) / xc (B) / out vec (final)
    __shared__ float sh_zv[DD];
    __shared__ float sh_yv[DD];
    __shared__ float sh_p[DD];       // matvec partials
    __shared__ float sh_x48[48];
    __shared__ float sh_cv[64];      // conv3 | conv_b (r<8 only)
    __shared__ float red[4];
    __shared__ float rstd_s;

    // ---------- part-1 prefetch: in_proj slice + conv + scalars ----------
    {
        const float4* Gi = (const float4*)(in_proj_w + (size_t)g * DD * 2 * DD) + r * 8;
        #pragma unroll
        for (int k = 0; k < 8; ++k) {
            const int m = tid + k * 256;               // m = d*8 + cg
            const int d = m >> 3, cg = m & 7;
            *(float4*)(dyn + L_IN + d * 32 + cg * 4) = Gi[(size_t)d * 128 + cg];
        }
        if (r < 8 && tid < 32) {
            const int gc = g * DD + r * 32 + tid;
            sh_cv[tid]      = conv_w[(size_t)gc * 4 + 3];
            sh_cv[32 + tid] = conv_b[gc];
        }
    }
    const float nw  = norm_w[g * DD + tid];
    const float nf  = norm_f_w[tid];
    const float dtb = dt_proj_b[g * DD + tid];
    const float dsk = D_skip[g * DD + tid];
    const float iv  = cls_token[tid] + pos_embed[50 * DD + tid];

    // ---------- part-2 prefetch (x_proj, dt_proj, out_proj) ----------
    auto prefetch2 = [&]() {
        const float4* Go = (const float4*)(out_proj_w + (size_t)g * DD * DD) + r * 4;
        #pragma unroll
        for (int k = 0; k < 4; ++k) {
            const int m = tid + k * 256;               // m = d*4 + c
            const int d = m >> 2, c = m & 3;
            *(float4*)(dyn + L_OUT + d * 16 + c * 4) = Go[(size_t)d * 64 + c];
        }
        const float4* Gx = (const float4*)(x_proj_w + (size_t)g * DD * 48);
        #pragma unroll
        for (int k = 0; k < 12; ++k) {
            const int m = tid + k * 256;               // 0..3071
            const int d = m / 12, c4 = m - d * 12;
            *(float4*)(dyn + L_XP + d * 52 + c4 * 4) = Gx[(size_t)d * 12 + c4];
        }
        const float4* Gd = (const float4*)(dt_proj_w + (size_t)g * 16 * DD);
        float4* Ld = (float4*)(dyn + L_DT);
        #pragma unroll
        for (int k = 0; k < 4; ++k) { const int m = tid + k * 256; Ld[m] = Gd[m]; }
    };

    // ---------- phase A: residual + rmsnorm + in_proj slice ----------
    auto phaseA = [&]() {
        if (g > 0) {
            if (tid == 0)
                while (llc_loadu(&flags[(4 + g - 1) * 32]) < WPL)
                    __builtin_amdgcn_s_sleep(1);
            __syncthreads();
        }
        const float rn = (g == 0) ? iv : llc_loadf(&res_g[g * DD + tid]);
        sh_res[tid] = rn;
        float ss = rn * rn;
        #pragma unroll
        for (int o = 32; o > 0; o >>= 1) ss += __shfl_down(ss, o, 64);
        if ((tid & 63) == 0) red[tid >> 6] = ss;
        __syncthreads();
        if (tid == 0)
            rstd_s = rsqrtf((red[0] + red[1] + red[2] + red[3]) * (1.f / DD) + 1e-5f);
        __syncthreads();
        sh_vec[tid] = rn * rstd_s * nw;
        __syncthreads();

        {   // in_proj: 32 cols; thread (c=tid&31, q=tid>>5), 2-way LDS (free)
            const int c = tid & 31, q = tid >> 5;
            float acc = 0.f;
            #pragma unroll
            for (int i = 0; i < 32; ++i) {
                const int d = q * 32 + i;
                acc += sh_vec[d] * dyn[L_IN + d * 32 + c];
            }
            sh_p[q * 32 + c] = acc;
        }
        __syncthreads();
        if (tid < 32) {
            float s = 0.f;
            #pragma unroll
            for (int p = 0; p < 8; ++p) s += sh_p[p * 32 + tid];
            const int gc = r * 32 + tid;
            if (r < 8) {
                const float pre = sh_cv[tid] * s + sh_cv[32 + tid];
                llc_storef(&xc_g[gc], pre / (1.f + __expf(-pre)));   // silu
            } else {
                llc_storef(&zv_g[gc - DD], s);
            }
        }
        __syncthreads();                 // drains sc1 stores (vmcnt 0)
        if (tid == 0) flag_add(&flags[g * 32]);                      // flagA[g]
    };

    // ---------- phase B: narrow path (redundant) + out_proj slice ----------
    auto phaseB = [&]() {
        if (tid == 0)
            while (llc_loadu(&flags[g * 32]) < WPL)
                __builtin_amdgcn_s_sleep(1);
        __syncthreads();
        sh_vec[tid] = llc_loadf(&xc_g[tid]);
        sh_zv[tid]  = llc_loadf(&zv_g[tid]);
        __syncthreads();

        if (tid < 192) {                 // x_proj: j=tid>>2, q=tid&3, d=i*4+q
            const int j = tid >> 2, q = tid & 3;
            float acc = 0.f;
            #pragma unroll 8
            for (int i = 0; i < 64; ++i) {
                const int d = i * 4 + q;
                acc += sh_vec[d] * dyn[L_XP + d * 52 + j];
            }
            sh_p[j * 4 + q] = acc;
        }
        __syncthreads();
        if (tid < 48)
            sh_x48[tid] = sh_p[tid * 4] + sh_p[tid * 4 + 1]
                        + sh_p[tid * 4 + 2] + sh_p[tid * 4 + 3];
        __syncthreads();
        {
            float acc = dtb;
            #pragma unroll
            for (int rr = 0; rr < 16; ++rr)
                acc += sh_x48[rr] * dyn[L_DT + rr * 256 + tid];
            const float dtv = fmaxf(acc, 0.f) + log1pf(__expf(-fabsf(acc))); // softplus
            float sbc = 0.f;
            #pragma unroll
            for (int n = 0; n < 16; ++n) sbc += sh_x48[16 + n] * sh_x48[32 + n]; // B.C
            const float y = (dtv * sbc + dsk) * sh_vec[tid];
            const float z = sh_zv[tid];
            sh_yv[tid] = y * (z / (1.f + __expf(-z)));                       // * silu(z)
        }
        __syncthreads();

        {   // out_proj: 16 cols; thread (c2=tid&15, q2=tid>>4), d=i*16+q2
            const int c2 = tid & 15, q2 = tid >> 4;
            float acc = 0.f;
            #pragma unroll
            for (int i = 0; i < 16; ++i) {
                const int d = i * 16 + q2;
                acc += sh_yv[d] * dyn[L_OUT + d * 16 + c2];
            }
            sh_p[q2 * 16 + c2] = acc;
        }
        __syncthreads();
        if (tid < 16) {
            float s = 0.f;
            #pragma unroll
            for (int p = 0; p < 16; ++p) s += sh_p[p * 16 + tid];
            const int gc = r * 16 + tid;
            if (g < 3) llc_storef(&res_g[(g + 1) * DD + gc], sh_res[gc] + s);
            else       llc_storef(&hv3_g[gc], s);    // final norm uses h only
        }
        __syncthreads();
        if (tid == 0) flag_add(&flags[(4 + g) * 32]);                // flagC[g]
    };

    if (g == 0) {
        __syncthreads();     // part-1 LDS visible
        phaseA();            // starts immediately (no flag wait)
        prefetch2();         // 85 KB overlaps the flagA hop
        __syncthreads();
    } else {
        prefetch2();
        __syncthreads();     // everything visible; then long flag wait
        phaseA();
    }
    phaseB();

    // ---------- final: rmsnorm(hv3) redundant; 4 rows per block ----------
    if (tid == 0)
        while (llc_loadu(&flags[(4 + 3) * 32]) < WPL)
            __builtin_amdgcn_s_sleep(1);
    __syncthreads();
    {
        const float x = llc_loadf(&hv3_g[tid]);
        float ss = x * x;
        #pragma unroll
        for (int o = 32; o > 0; o >>= 1) ss += __shfl_down(ss, o, 64);
        if ((tid & 63) == 0) red[tid >> 6] = ss;
        __syncthreads();
        if (tid == 0)
            rstd_s = rsqrtf((red[0] + red[1] + red[2] + red[3]) * (1.f / DD) + 1e-5f);
        __syncthreads();
        sh_vec[tid] = x * rstd_s * nf;
    }
    __syncthreads();
    {
        const int row = bid * 4 + (tid >> 6);
        const int cc  = tid & 63;
        const float4 v = make_float4(sh_vec[cc * 4], sh_vec[cc * 4 + 1],
                                     sh_vec[cc * 4 + 2], sh_vec[cc * 4 + 3]);
        ((float4*)out)[(size_t)row * 64 + cc] = v;
    }
}

extern "C" void kernel_launch(void* const* d_in, const int* in_sizes, int n_in,
                              void* d_out, int out_size, void* d_ws, size_t ws_size,
                              hipStream_t stream) {
    // 0 x, 1 proj_w, 2 proj_b, 3 cls_token, 4 pos_embed, 5 norm_w, 6 in_proj_w,
    // 7 conv_w, 8 conv_b, 9 x_proj_w, 10 dt_proj_w, 11 dt_proj_b, 12 A_log,
    // 13 D_skip, 14 out_proj_w, 15 norm_f_w
    float* ws = (float*)d_ws;
    unsigned* flags = (unsigned*)(ws + WS_FLAG);

    netmamba_init<<<dim3(1), dim3(256), 0, stream>>>(flags);
    netmamba_df2<<<dim3(NBLK), dim3(NTHR), DYN_FLOATS * sizeof(float), stream>>>(
        (const float*)d_in[3], (const float*)d_in[4], (const float*)d_in[5],
        (const float*)d_in[6], (const float*)d_in[7], (const float*)d_in[8],
        (const float*)d_in[9], (const float*)d_in[10], (const float*)d_in[11],
        (const float*)d_in[13], (const float*)d_in[14], (const float*)d_in[15],
        (float*)d_out, ws);
}